// Round 25
// baseline (769.726 us; speedup 1.0000x reference)
//
#include <hip/hip_runtime.h>
#include <math.h>

#define B_SZ 8192
#define H_SZ 2048
#define I_SZ 1024
#define O_SZ 512

typedef double v4d __attribute__((ext_vector_type(4)));
typedef float v4f __attribute__((ext_vector_type(4)));
typedef short v8bf __attribute__((ext_vector_type(8)));

// ======== f32 math mirroring numpy float32 semantics (r13-proven) ========

__device__ __forceinline__ float signf_(float x) {
    return (x > 0.f) ? 1.f : ((x < 0.f) ? -1.f : 0.f);
}

__device__ __forceinline__ float next_spike_f32(float v, float eta) {
#pragma clang fp contract(off)
    const float EPSf = 1e-6f;
    const float HEPSf = (float)(0.5 * 1e-6);
    const float T_INF = 10000.f;
    const float PI_F = (float)3.14159265358979323846;
    float ae = fabsf(eta) + EPSf;
    float se = (float)sqrt((double)ae);        // correctly-rounded f32 sqrt
    float s1 = signf_(v);
    float t1 = EPSf * s1;
    float va = v + t1;
    float vpe = v + EPSf;
    float s2 = signf_(vpe);
    float t2 = HEPSf * s2;
    float vs = va + t2;                        // ((v + e*s1) + he*s2)
    if (eta == 0.f) {
        if (v > 0.f) return 1.f / vs;
        return T_INF;
    }
    if (eta < 0.f) {
        if (v > se) {
            float r = se / vs;
            const float lo = (float)(-1.0 + 1e-6);
            const float hi = (float)(1.0 - 1e-6);
            r = fminf(fmaxf(r, lo), hi);
            float at = atanhf(r);              // ocml
            return at / se;
        }
        return T_INF;
    }
    float q = se / vs;
    float a = atanf(q);                        // ocml
    if (a < 0.f) a = a + PI_F;                 // np.mod(a, pi) for |a| < pi
    return a / se;
}

__device__ __forceinline__ float update_pot_f32(float v, float eta, float dt) {
#pragma clang fp contract(off)
    const float EPSf = 1e-6f;
    float ae = fabsf(eta) + EPSf;
    float se = (float)sqrt((double)ae);
    float r;
    if (eta == 0.f) {
        float t1 = dt * v;
        float den = 1.f - t1;
        r = v / den;
    } else if (eta < 0.f) {
        float x = se * dt;
        float th = tanhf(x);                   // ocml
        float t1 = se * th;
        float num = v - t1;
        float t2 = th * v;
        float t3 = t2 / se;
        float den = 1.f - t3;
        r = num / den;
    } else {
        float x = se * dt;
        float ta = tanf(x);                    // ocml
        float t1 = se * ta;
        float num = v + t1;
        float t2 = ta * v;
        float t3 = t2 / se;
        float den = 1.f - t3;
        r = num / den;
    }
    const float HI = (float)1e25;
    r = r < -HI ? -HI : (r > HI ? HI : r);     // NaN passes through, like np.clip
    return r;
}

// ---------------- transpose (32x32 LDS tiles) ----------------

__global__ __launch_bounds__(256) void transpose_kernel(const float* __restrict__ in,
                                                        float* __restrict__ out,
                                                        int R, int C) {
    __shared__ float tile[32][33];
    int bx = blockIdx.x * 32;
    int by = blockIdx.y * 32;
    int tx = threadIdx.x;
    int ty = threadIdx.y;
#pragma unroll
    for (int i = ty; i < 32; i += 8)
        tile[i][tx] = in[(size_t)(by + i) * C + bx + tx];
    __syncthreads();
#pragma unroll
    for (int i = ty; i < 32; i += 8)
        out[(size_t)(bx + i) * R + by + tx] = tile[tx][i];
}

// ---------------- eta GEMM: f64 MFMA, 8 waves, async-DMA dbuf LDS (r19) + setprio ----------------

#define EBK 32

__device__ __forceinline__ void stage_tile_dma(
    const float* __restrict__ A, const float* __restrict__ Bm,
    float (*Asb)[32], float (*Bsb)[32],
    int row0, int col0, int k0, int tid) {
    const int wid = tid >> 6;                       // 0..7
    const int lane = tid & 63;
    const int sr8 = lane >> 3;                      // row within 8-row group
    const int ksw = ((lane & 7) ^ sr8) << 2;        // swizzled float offset
#pragma unroll
    for (int p = 0; p < 2; ++p) {
        const int rbase = p * 64 + wid * 8;         // wave-uniform
        const float* ga = A + (size_t)(row0 + rbase + sr8) * I_SZ + k0 + ksw;
        const float* gb = Bm + (size_t)(col0 + rbase + sr8) * I_SZ + k0 + ksw;
        float* la = &Asb[rbase][0];                 // wave-uniform base
        float* lb = &Bsb[rbase][0];
        __builtin_amdgcn_global_load_lds(
            (const __attribute__((address_space(1))) void*)ga,
            (__attribute__((address_space(3))) void*)la, 16, 0, 0);
        __builtin_amdgcn_global_load_lds(
            (const __attribute__((address_space(1))) void*)gb,
            (__attribute__((address_space(3))) void*)lb, 16, 0, 0);
    }
}

__global__ __launch_bounds__(512) void gemm_eta_mfma_f64(
    const float* __restrict__ A,    // [B,I]
    const float* __restrict__ Bm,   // [H,I]
    const float* __restrict__ b_i2h, const float* __restrict__ b_h2h,
    float* __restrict__ C) {
    __shared__ float As[2][128][32];
    __shared__ float Bs[2][128][32];
    const int tid = threadIdx.x;
    const int row0 = blockIdx.y * 128;   // batch rows
    const int col0 = blockIdx.x * 128;   // H cols
    const int wid = tid >> 6;            // wave 0..7
    const int lane = tid & 63;
    const int wrow = wid >> 1;           // 0..3 (32-row band)
    const int wcol = wid & 1;            // 0..1 (64-col band)
    const int lr = lane & 15;            // fragment row/col-in-16
    const int lk = lane >> 4;            // fragment k-in-4 / D row group
    const int csw = (lr & 7) << 2;       // read-side XOR swizzle

    v4d acc[2][4];
#pragma unroll
    for (int i = 0; i < 2; ++i)
#pragma unroll
        for (int j = 0; j < 4; ++j) acc[i][j] = (v4d){0.0, 0.0, 0.0, 0.0};

    stage_tile_dma(A, Bm, As[0], Bs[0], row0, col0, 0, tid);
    __syncthreads();

    int cur = 0;
    for (int k0 = 0; k0 < I_SZ; k0 += EBK) {
        int knext = k0 + EBK;
        if (knext < I_SZ)   // async DMA into other buffer; hides under MFMA
            stage_tile_dma(A, Bm, As[cur ^ 1], Bs[cur ^ 1], row0, col0, knext, tid);
#pragma unroll
        for (int ks = 0; ks < EBK / 4; ++ks) {   // ascending k, K=4 per mfma
            int kk = ks * 4 + lk;
            int kks = kk ^ csw;                  // swizzled col
            double a[2], b[4];
#pragma unroll
            for (int i = 0; i < 2; ++i)
                a[i] = (double)As[cur][wrow * 32 + i * 16 + lr][kks];
#pragma unroll
            for (int j = 0; j < 4; ++j)
                b[j] = (double)Bs[cur][wcol * 64 + j * 16 + lr][kks];
            __builtin_amdgcn_s_setprio(1);       // favor MFMA-issuing waves
#pragma unroll
            for (int i = 0; i < 2; ++i)
#pragma unroll
                for (int j = 0; j < 4; ++j)
                    acc[i][j] = __builtin_amdgcn_mfma_f64_16x16x4f64(
                        a[i], b[j], acc[i][j], 0, 0, 0);
            __builtin_amdgcn_s_setprio(0);
        }
        __syncthreads();   // drains DMA (vmcnt) + LDS reads before buffer swap
        cur ^= 1;
    }
    {
#pragma clang fp contract(off)
#pragma unroll
        for (int i = 0; i < 2; ++i) {
#pragma unroll
            for (int j = 0; j < 4; ++j) {
                int gcol = col0 + wcol * 64 + j * 16 + lr;
#pragma unroll
                for (int q = 0; q < 4; ++q) {
                    // STRIDED D layout: row = 4*reg + (lane>>4)
                    int grow = row0 + wrow * 32 + i * 16 + q * 4 + lk;
                    float m32 = (float)acc[i][j][q];    // f32 of f64-accurate dot
                    float s = b_h2h[gcol] + m32;        // (b_h2h + M)
                    s = s + b_i2h[gcol];                // + b_i2h
                    C[(size_t)grow * H_SZ + gcol] = s;
                }
            }
        }
    }
}

// ---------------- FUSED: next_spike + min/argmin + update_v + out_spike (r21) ----------------

__global__ __launch_bounds__(256) void fused_row_kernel(
    const float* __restrict__ v_in, const float* __restrict__ spike,
    const float* __restrict__ eta, const float* __restrict__ t_in,
    const float* __restrict__ syn_p,
    const float* __restrict__ whhT, const float* __restrict__ whoT,
    float* __restrict__ t_out, float* __restrict__ mdt_out,
    float* __restrict__ kf_out, int* __restrict__ kidx_out,
    float* __restrict__ v_out, float* __restrict__ out0) {
#pragma clang fp contract(off)
    const int b = blockIdx.x;
    const int tid = threadIdx.x;
    const size_t base = (size_t)b * H_SZ;
    const int h0 = tid * 4;
    const int h1 = tid * 4 + 1024;

    float4 v0 = *reinterpret_cast<const float4*>(v_in + base + h0);
    float4 v1 = *reinterpret_cast<const float4*>(v_in + base + h1);
    float4 s0 = *reinterpret_cast<const float4*>(spike + base + h0);
    float4 s1 = *reinterpret_cast<const float4*>(spike + base + h1);
    float4 e0 = *reinterpret_cast<const float4*>(eta + base + h0);
    float4 e1 = *reinterpret_cast<const float4*>(eta + base + h1);

    float vv[8] = {v0.x + s0.x, v0.y + s0.y, v0.z + s0.z, v0.w + s0.w,
                   v1.x + s1.x, v1.y + s1.y, v1.z + s1.z, v1.w + s1.w};
    float ee[8] = {e0.x, e0.y, e0.z, e0.w, e1.x, e1.y, e1.z, e1.w};

    unsigned long long best = 0xFFFFFFFFFFFFFFFFull;
#pragma unroll
    for (int q = 0; q < 8; ++q) {
        int h = (q < 4) ? (h0 + q) : (h1 + q - 4);
        float dt = next_spike_f32(vv[q], ee[q]);
        unsigned long long p =
            ((unsigned long long)__float_as_uint(dt) << 32) | (unsigned)h;
        best = (p < best) ? p : best;
    }
#pragma unroll
    for (int off = 1; off < 64; off <<= 1) {
        unsigned long long o = __shfl_xor(best, off);
        best = (o < best) ? o : best;
    }
    __shared__ unsigned long long s[4];
    if ((tid & 63) == 0) s[tid >> 6] = best;
    __syncthreads();
    best = s[0];
#pragma unroll
    for (int w = 1; w < 4; ++w)
        if (s[w] < best) best = s[w];
    float mdt = __uint_as_float((unsigned)(best >> 32));
    int k = (int)(best & 0xFFFFFFFFu);
    float syn = *syn_p;

    if (tid == 0) {
        mdt_out[b] = mdt;
        kf_out[b] = (float)k;
        kidx_out[b] = k;
        float tt = t_in[b] + mdt;   // np: (t + min_dt) + syn_delay
        tt = tt + syn;
        t_out[b] = tt;
    }

    float dtq = mdt + syn;          // one f32 rounding
    float4 w0 = *reinterpret_cast<const float4*>(whhT + (size_t)k * H_SZ + h0);
    float4 w1 = *reinterpret_cast<const float4*>(whhT + (size_t)k * H_SZ + h1);
    float4 r0, r1;
    r0.x = update_pot_f32(vv[0], ee[0], dtq) + w0.x;
    r0.y = update_pot_f32(vv[1], ee[1], dtq) + w0.y;
    r0.z = update_pot_f32(vv[2], ee[2], dtq) + w0.z;
    r0.w = update_pot_f32(vv[3], ee[3], dtq) + w0.w;
    r1.x = update_pot_f32(vv[4], ee[4], dtq) + w1.x;
    r1.y = update_pot_f32(vv[5], ee[5], dtq) + w1.y;
    r1.z = update_pot_f32(vv[6], ee[6], dtq) + w1.z;
    r1.w = update_pot_f32(vv[7], ee[7], dtq) + w1.w;
    *reinterpret_cast<float4*>(v_out + base + h0) = r0;
    *reinterpret_cast<float4*>(v_out + base + h1) = r1;

    if (tid < 128) {
        float4 w = *reinterpret_cast<const float4*>(whoT + (size_t)k * O_SZ + tid * 4);
        *reinterpret_cast<float4*>(out0 + (size_t)b * O_SZ + tid * 4) = w;
    }
}

// ---------------- bf16 split helpers ----------------

__device__ __forceinline__ unsigned short bf16_rn(float x) {
    unsigned u = __float_as_uint(x);
    unsigned r = (u + 0x7fffu + ((u >> 16) & 1u)) >> 16;
    return (unsigned short)r;
}

// precompute w_h2o bf16 hi/lo split once
__global__ __launch_bounds__(256) void split_w_kernel(
    const float* __restrict__ W, unsigned short* __restrict__ Wh,
    unsigned short* __restrict__ Wl, int n) {
    int i = blockIdx.x * 256 + threadIdx.x;
    if (i * 4 >= n) return;
    float4 w4 = *reinterpret_cast<const float4*>(W + i * 4);
    float wv[4] = {w4.x, w4.y, w4.z, w4.w};
    unsigned short h4[4], l4[4];
#pragma unroll
    for (int e = 0; e < 4; ++e) {
        h4[e] = bf16_rn(wv[e]);
        float hf = __uint_as_float((unsigned)h4[e] << 16);
        l4[e] = bf16_rn(wv[e] - hf);
    }
    *reinterpret_cast<ushort4*>(Wh + i * 4) = make_ushort4(h4[0], h4[1], h4[2], h4[3]);
    *reinterpret_cast<ushort4*>(Wl + i * 4) = make_ushort4(l4[0], l4[1], l4[2], l4[3]);
}

// ---------------- output_potential GEMM: bf16x3 split MFMA, pre-split B (r22) + setprio ----------------

#define OBK 32

__global__ __launch_bounds__(256) void gemm_out1_bf16x3(
    const float* __restrict__ A,    // out_v [B,H]
    const unsigned short* __restrict__ Bh_g,   // pre-split w_h2o hi [O,H]
    const unsigned short* __restrict__ Bl_g,   // pre-split w_h2o lo [O,H]
    const float* __restrict__ bias0, float* __restrict__ C,
    const float* __restrict__ vminp, const float* __restrict__ vmaxp) {
    __shared__ unsigned short Ah[64][40], Al[64][40];
    __shared__ unsigned short Bh[64][40], Bl[64][40];
    const int tid = threadIdx.x;
    const int row0 = blockIdx.y * 64;   // batch rows
    const int col0 = blockIdx.x * 64;   // O cols
    const float vmin = *vminp, vmax = *vmaxp;
    const int wid = tid >> 6, lane = tid & 63;
    const int wrow = wid >> 1, wcol = wid & 1;
    const int lr = lane & 15;           // frag row/col
    const int lg = lane >> 4;           // k-group / D row group
    const int srow = tid >> 2;          // 0..63 staging row
    const int scol = (tid & 3) * 8;     // 0,8,16,24

    v4f acc[2][2];
#pragma unroll
    for (int i = 0; i < 2; ++i)
#pragma unroll
        for (int j = 0; j < 2; ++j) acc[i][j] = (v4f){0.f, 0.f, 0.f, 0.f};

    for (int k0 = 0; k0 < H_SZ; k0 += OBK) {
        // B staging: pure coalesced ushort copies (split precomputed)
        {
            ushort4 bh0 = *reinterpret_cast<const ushort4*>(
                Bh_g + (size_t)(col0 + srow) * H_SZ + k0 + scol);
            ushort4 bh1 = *reinterpret_cast<const ushort4*>(
                Bh_g + (size_t)(col0 + srow) * H_SZ + k0 + scol + 4);
            ushort4 bl0 = *reinterpret_cast<const ushort4*>(
                Bl_g + (size_t)(col0 + srow) * H_SZ + k0 + scol);
            ushort4 bl1 = *reinterpret_cast<const ushort4*>(
                Bl_g + (size_t)(col0 + srow) * H_SZ + k0 + scol + 4);
            *reinterpret_cast<ushort4*>(&Bh[srow][scol]) = bh0;
            *reinterpret_cast<ushort4*>(&Bh[srow][scol + 4]) = bh1;
            *reinterpret_cast<ushort4*>(&Bl[srow][scol]) = bl0;
            *reinterpret_cast<ushort4*>(&Bl[srow][scol + 4]) = bl1;
        }
        // A staging: load f32, clip, split (8x redundancy only)
#pragma unroll
        for (int p = 0; p < 2; ++p) {
            float4 a4 = *reinterpret_cast<const float4*>(
                A + (size_t)(row0 + srow) * H_SZ + k0 + scol + p * 4);
            float av[4] = {fminf(fmaxf(a4.x, vmin), vmax),
                           fminf(fmaxf(a4.y, vmin), vmax),
                           fminf(fmaxf(a4.z, vmin), vmax),
                           fminf(fmaxf(a4.w, vmin), vmax)};
#pragma unroll
            for (int e = 0; e < 4; ++e) {
                int cc = scol + p * 4 + e;
                unsigned short ha = bf16_rn(av[e]);
                float hfa = __uint_as_float((unsigned)ha << 16);
                Ah[srow][cc] = ha;
                Al[srow][cc] = bf16_rn(av[e] - hfa);
            }
        }
        __syncthreads();
        v8bf ah[2], al[2], bh[2], bl[2];
#pragma unroll
        for (int i = 0; i < 2; ++i) {
            ah[i] = *reinterpret_cast<const v8bf*>(&Ah[wrow * 32 + i * 16 + lr][lg * 8]);
            al[i] = *reinterpret_cast<const v8bf*>(&Al[wrow * 32 + i * 16 + lr][lg * 8]);
        }
#pragma unroll
        for (int j = 0; j < 2; ++j) {
            bh[j] = *reinterpret_cast<const v8bf*>(&Bh[wcol * 32 + j * 16 + lr][lg * 8]);
            bl[j] = *reinterpret_cast<const v8bf*>(&Bl[wcol * 32 + j * 16 + lr][lg * 8]);
        }
        __builtin_amdgcn_s_setprio(1);
#pragma unroll
        for (int i = 0; i < 2; ++i)
#pragma unroll
            for (int j = 0; j < 2; ++j) {
                acc[i][j] = __builtin_amdgcn_mfma_f32_16x16x32_bf16(
                    ah[i], bh[j], acc[i][j], 0, 0, 0);
                acc[i][j] = __builtin_amdgcn_mfma_f32_16x16x32_bf16(
                    ah[i], bl[j], acc[i][j], 0, 0, 0);
                acc[i][j] = __builtin_amdgcn_mfma_f32_16x16x32_bf16(
                    al[i], bh[j], acc[i][j], 0, 0, 0);
            }
        __builtin_amdgcn_s_setprio(0);
        __syncthreads();
    }
#pragma unroll
    for (int i = 0; i < 2; ++i)
#pragma unroll
        for (int j = 0; j < 2; ++j) {
            int gcol = col0 + wcol * 32 + j * 16 + lr;
            float bb = bias0[gcol];
#pragma unroll
            for (int q = 0; q < 4; ++q) {
                int grow = row0 + wrow * 32 + i * 16 + lg * 4 + q;  // blocked D
                C[(size_t)grow * O_SZ + gcol] = acc[i][j][q] + bb;
            }
        }
}

// ---------------- launch ----------------

extern "C" void kernel_launch(void* const* d_in, const int* in_sizes, int n_in,
                              void* d_out, int out_size, void* d_ws, size_t ws_size,
                              hipStream_t stream) {
    const float* in_spike = (const float*)d_in[0];
    const float* in_cur   = (const float*)d_in[1];
    const float* v_in     = (const float*)d_in[2];
    const float* t_in     = (const float*)d_in[3];
    const float* w_i2h    = (const float*)d_in[4];
    const float* b_i2h    = (const float*)d_in[5];
    const float* w_h2h    = (const float*)d_in[6];
    const float* b_h2h    = (const float*)d_in[7];
    const float* w_h2o    = (const float*)d_in[8];
    const float* b_h2o    = (const float*)d_in[9];
    const float* syn_p    = (const float*)d_in[10];
    const float* vmin_p   = (const float*)d_in[11];
    const float* vmax_p   = (const float*)d_in[12];

    float* out0    = (float*)d_out;                     // output_spike [B,O]
    float* out1    = out0 + (size_t)B_SZ * O_SZ;        // output_potential [B,O]
    float* out_v   = out1 + (size_t)B_SZ * O_SZ;        // v [B,H]
    float* out_t   = out_v + (size_t)B_SZ * H_SZ;       // t [B]
    float* out_mdt = out_t + B_SZ;                      // min_dt [B]
    float* out_kf  = out_mdt + B_SZ;                    // k (float) [B]

    // workspace: eta f32 [B,H] | kidx int [B] | whhT [H,H] | whoT [H,O]
    //            | Wh2o_hi ushort [O,H] | Wh2o_lo ushort [O,H]
    float* eta  = (float*)d_ws;
    int*   kidx = (int*)(eta + (size_t)B_SZ * H_SZ);
    float* whhT = (float*)(kidx + B_SZ);
    float* whoT = whhT + (size_t)H_SZ * H_SZ;
    unsigned short* Wh = (unsigned short*)(whoT + (size_t)H_SZ * O_SZ);
    unsigned short* Wl = Wh + (size_t)O_SZ * H_SZ;

    dim3 tb(32, 8);
    transpose_kernel<<<dim3(H_SZ / 32, H_SZ / 32), tb, 0, stream>>>(w_h2h, whhT,
                                                                    H_SZ, H_SZ);
    transpose_kernel<<<dim3(H_SZ / 32, O_SZ / 32), tb, 0, stream>>>(w_h2o, whoT,
                                                                    O_SZ, H_SZ);
    split_w_kernel<<<(O_SZ * H_SZ / 4 + 255) / 256, 256, 0, stream>>>(
        w_h2o, Wh, Wl, O_SZ * H_SZ);

    gemm_eta_mfma_f64<<<dim3(H_SZ / 128, B_SZ / 128), 512, 0, stream>>>(
        in_cur, w_i2h, b_i2h, b_h2h, eta);

    fused_row_kernel<<<B_SZ, 256, 0, stream>>>(
        v_in, in_spike, eta, t_in, syn_p, whhT, whoT,
        out_t, out_mdt, out_kf, kidx, out_v, out0);

    gemm_out1_bf16x3<<<dim3(O_SZ / 64, B_SZ / 64), 256, 0, stream>>>(
        out_v, Wh, Wl, b_h2o, out1, vmin_p, vmax_p);
}

// Round 26
// 756.919 us; speedup vs baseline: 1.0169x; 1.0169x over previous
//
#include <hip/hip_runtime.h>
#include <math.h>

#define B_SZ 8192
#define H_SZ 2048
#define I_SZ 1024
#define O_SZ 512

typedef double v4d __attribute__((ext_vector_type(4)));
typedef float v4f __attribute__((ext_vector_type(4)));
typedef short v8bf __attribute__((ext_vector_type(8)));

// ======== f32 math mirroring numpy float32 semantics (r13-proven) ========

__device__ __forceinline__ float signf_(float x) {
    return (x > 0.f) ? 1.f : ((x < 0.f) ? -1.f : 0.f);
}

__device__ __forceinline__ float next_spike_f32(float v, float eta) {
#pragma clang fp contract(off)
    const float EPSf = 1e-6f;
    const float HEPSf = (float)(0.5 * 1e-6);
    const float T_INF = 10000.f;
    const float PI_F = (float)3.14159265358979323846;
    float ae = fabsf(eta) + EPSf;
    float se = (float)sqrt((double)ae);        // correctly-rounded f32 sqrt
    float s1 = signf_(v);
    float t1 = EPSf * s1;
    float va = v + t1;
    float vpe = v + EPSf;
    float s2 = signf_(vpe);
    float t2 = HEPSf * s2;
    float vs = va + t2;                        // ((v + e*s1) + he*s2)
    if (eta == 0.f) {
        if (v > 0.f) return 1.f / vs;
        return T_INF;
    }
    if (eta < 0.f) {
        if (v > se) {
            float r = se / vs;
            const float lo = (float)(-1.0 + 1e-6);
            const float hi = (float)(1.0 - 1e-6);
            r = fminf(fmaxf(r, lo), hi);
            float at = atanhf(r);              // ocml
            return at / se;
        }
        return T_INF;
    }
    float q = se / vs;
    float a = atanf(q);                        // ocml
    if (a < 0.f) a = a + PI_F;                 // np.mod(a, pi) for |a| < pi
    return a / se;
}

__device__ __forceinline__ float update_pot_f32(float v, float eta, float dt) {
#pragma clang fp contract(off)
    const float EPSf = 1e-6f;
    float ae = fabsf(eta) + EPSf;
    float se = (float)sqrt((double)ae);
    float r;
    if (eta == 0.f) {
        float t1 = dt * v;
        float den = 1.f - t1;
        r = v / den;
    } else if (eta < 0.f) {
        float x = se * dt;
        float th = tanhf(x);                   // ocml
        float t1 = se * th;
        float num = v - t1;
        float t2 = th * v;
        float t3 = t2 / se;
        float den = 1.f - t3;
        r = num / den;
    } else {
        float x = se * dt;
        float ta = tanf(x);                    // ocml
        float t1 = se * ta;
        float num = v + t1;
        float t2 = ta * v;
        float t3 = t2 / se;
        float den = 1.f - t3;
        r = num / den;
    }
    const float HI = (float)1e25;
    r = r < -HI ? -HI : (r > HI ? HI : r);     // NaN passes through, like np.clip
    return r;
}

// ---------------- transpose (32x32 LDS tiles) ----------------

__global__ __launch_bounds__(256) void transpose_kernel(const float* __restrict__ in,
                                                        float* __restrict__ out,
                                                        int R, int C) {
    __shared__ float tile[32][33];
    int bx = blockIdx.x * 32;
    int by = blockIdx.y * 32;
    int tx = threadIdx.x;
    int ty = threadIdx.y;
#pragma unroll
    for (int i = ty; i < 32; i += 8)
        tile[i][tx] = in[(size_t)(by + i) * C + bx + tx];
    __syncthreads();
#pragma unroll
    for (int i = ty; i < 32; i += 8)
        out[(size_t)(bx + i) * R + by + tx] = tile[tx][i];
}

// ---------------- eta GEMM: f64 MFMA, 8 waves, async-DMA dbuf LDS (r19) ----------------

#define EBK 32

__device__ __forceinline__ void stage_tile_dma(
    const float* __restrict__ A, const float* __restrict__ Bm,
    float (*Asb)[32], float (*Bsb)[32],
    int row0, int col0, int k0, int tid) {
    const int wid = tid >> 6;                       // 0..7
    const int lane = tid & 63;
    const int sr8 = lane >> 3;                      // row within 8-row group
    const int ksw = ((lane & 7) ^ sr8) << 2;        // swizzled float offset
#pragma unroll
    for (int p = 0; p < 2; ++p) {
        const int rbase = p * 64 + wid * 8;         // wave-uniform
        const float* ga = A + (size_t)(row0 + rbase + sr8) * I_SZ + k0 + ksw;
        const float* gb = Bm + (size_t)(col0 + rbase + sr8) * I_SZ + k0 + ksw;
        float* la = &Asb[rbase][0];                 // wave-uniform base
        float* lb = &Bsb[rbase][0];
        __builtin_amdgcn_global_load_lds(
            (const __attribute__((address_space(1))) void*)ga,
            (__attribute__((address_space(3))) void*)la, 16, 0, 0);
        __builtin_amdgcn_global_load_lds(
            (const __attribute__((address_space(1))) void*)gb,
            (__attribute__((address_space(3))) void*)lb, 16, 0, 0);
    }
}

__global__ __launch_bounds__(512) void gemm_eta_mfma_f64(
    const float* __restrict__ A,    // [B,I]
    const float* __restrict__ Bm,   // [H,I]
    const float* __restrict__ b_i2h, const float* __restrict__ b_h2h,
    float* __restrict__ C) {
    __shared__ float As[2][128][32];
    __shared__ float Bs[2][128][32];
    const int tid = threadIdx.x;
    const int row0 = blockIdx.y * 128;   // batch rows
    const int col0 = blockIdx.x * 128;   // H cols
    const int wid = tid >> 6;            // wave 0..7
    const int lane = tid & 63;
    const int wrow = wid >> 1;           // 0..3 (32-row band)
    const int wcol = wid & 1;            // 0..1 (64-col band)
    const int lr = lane & 15;            // fragment row/col-in-16
    const int lk = lane >> 4;            // fragment k-in-4 / D row group
    const int csw = (lr & 7) << 2;       // read-side XOR swizzle

    v4d acc[2][4];
#pragma unroll
    for (int i = 0; i < 2; ++i)
#pragma unroll
        for (int j = 0; j < 4; ++j) acc[i][j] = (v4d){0.0, 0.0, 0.0, 0.0};

    stage_tile_dma(A, Bm, As[0], Bs[0], row0, col0, 0, tid);
    __syncthreads();

    int cur = 0;
    for (int k0 = 0; k0 < I_SZ; k0 += EBK) {
        int knext = k0 + EBK;
        if (knext < I_SZ)   // async DMA into other buffer; hides under MFMA
            stage_tile_dma(A, Bm, As[cur ^ 1], Bs[cur ^ 1], row0, col0, knext, tid);
#pragma unroll
        for (int ks = 0; ks < EBK / 4; ++ks) {   // ascending k, K=4 per mfma
            int kk = ks * 4 + lk;
            int kks = kk ^ csw;                  // swizzled col
            double a[2], b[4];
#pragma unroll
            for (int i = 0; i < 2; ++i)
                a[i] = (double)As[cur][wrow * 32 + i * 16 + lr][kks];
#pragma unroll
            for (int j = 0; j < 4; ++j)
                b[j] = (double)Bs[cur][wcol * 64 + j * 16 + lr][kks];
#pragma unroll
            for (int i = 0; i < 2; ++i)
#pragma unroll
                for (int j = 0; j < 4; ++j)
                    acc[i][j] = __builtin_amdgcn_mfma_f64_16x16x4f64(
                        a[i], b[j], acc[i][j], 0, 0, 0);
        }
        __syncthreads();   // drains DMA (vmcnt) + LDS reads before buffer swap
        cur ^= 1;
    }
    {
#pragma clang fp contract(off)
#pragma unroll
        for (int i = 0; i < 2; ++i) {
#pragma unroll
            for (int j = 0; j < 4; ++j) {
                int gcol = col0 + wcol * 64 + j * 16 + lr;
#pragma unroll
                for (int q = 0; q < 4; ++q) {
                    // STRIDED D layout: row = 4*reg + (lane>>4)
                    int grow = row0 + wrow * 32 + i * 16 + q * 4 + lk;
                    float m32 = (float)acc[i][j][q];    // f32 of f64-accurate dot
                    float s = b_h2h[gcol] + m32;        // (b_h2h + M)
                    s = s + b_i2h[gcol];                // + b_i2h
                    C[(size_t)grow * H_SZ + gcol] = s;
                }
            }
        }
    }
}

// ---------------- FUSED: next_spike + min/argmin + update_v + out_spike (r21) ----------------

__global__ __launch_bounds__(256) void fused_row_kernel(
    const float* __restrict__ v_in, const float* __restrict__ spike,
    const float* __restrict__ eta, const float* __restrict__ t_in,
    const float* __restrict__ syn_p,
    const float* __restrict__ whhT, const float* __restrict__ whoT,
    float* __restrict__ t_out, float* __restrict__ mdt_out,
    float* __restrict__ kf_out, int* __restrict__ kidx_out,
    float* __restrict__ v_out, float* __restrict__ out0) {
#pragma clang fp contract(off)
    const int b = blockIdx.x;
    const int tid = threadIdx.x;
    const size_t base = (size_t)b * H_SZ;
    const int h0 = tid * 4;
    const int h1 = tid * 4 + 1024;

    float4 v0 = *reinterpret_cast<const float4*>(v_in + base + h0);
    float4 v1 = *reinterpret_cast<const float4*>(v_in + base + h1);
    float4 s0 = *reinterpret_cast<const float4*>(spike + base + h0);
    float4 s1 = *reinterpret_cast<const float4*>(spike + base + h1);
    float4 e0 = *reinterpret_cast<const float4*>(eta + base + h0);
    float4 e1 = *reinterpret_cast<const float4*>(eta + base + h1);

    float vv[8] = {v0.x + s0.x, v0.y + s0.y, v0.z + s0.z, v0.w + s0.w,
                   v1.x + s1.x, v1.y + s1.y, v1.z + s1.z, v1.w + s1.w};
    float ee[8] = {e0.x, e0.y, e0.z, e0.w, e1.x, e1.y, e1.z, e1.w};

    unsigned long long best = 0xFFFFFFFFFFFFFFFFull;
#pragma unroll
    for (int q = 0; q < 8; ++q) {
        int h = (q < 4) ? (h0 + q) : (h1 + q - 4);
        float dt = next_spike_f32(vv[q], ee[q]);
        unsigned long long p =
            ((unsigned long long)__float_as_uint(dt) << 32) | (unsigned)h;
        best = (p < best) ? p : best;
    }
#pragma unroll
    for (int off = 1; off < 64; off <<= 1) {
        unsigned long long o = __shfl_xor(best, off);
        best = (o < best) ? o : best;
    }
    __shared__ unsigned long long s[4];
    if ((tid & 63) == 0) s[tid >> 6] = best;
    __syncthreads();
    best = s[0];
#pragma unroll
    for (int w = 1; w < 4; ++w)
        if (s[w] < best) best = s[w];
    float mdt = __uint_as_float((unsigned)(best >> 32));
    int k = (int)(best & 0xFFFFFFFFu);
    float syn = *syn_p;

    if (tid == 0) {
        mdt_out[b] = mdt;
        kf_out[b] = (float)k;
        kidx_out[b] = k;
        float tt = t_in[b] + mdt;   // np: (t + min_dt) + syn_delay
        tt = tt + syn;
        t_out[b] = tt;
    }

    float dtq = mdt + syn;          // one f32 rounding
    float4 w0 = *reinterpret_cast<const float4*>(whhT + (size_t)k * H_SZ + h0);
    float4 w1 = *reinterpret_cast<const float4*>(whhT + (size_t)k * H_SZ + h1);
    float4 r0, r1;
    r0.x = update_pot_f32(vv[0], ee[0], dtq) + w0.x;
    r0.y = update_pot_f32(vv[1], ee[1], dtq) + w0.y;
    r0.z = update_pot_f32(vv[2], ee[2], dtq) + w0.z;
    r0.w = update_pot_f32(vv[3], ee[3], dtq) + w0.w;
    r1.x = update_pot_f32(vv[4], ee[4], dtq) + w1.x;
    r1.y = update_pot_f32(vv[5], ee[5], dtq) + w1.y;
    r1.z = update_pot_f32(vv[6], ee[6], dtq) + w1.z;
    r1.w = update_pot_f32(vv[7], ee[7], dtq) + w1.w;
    *reinterpret_cast<float4*>(v_out + base + h0) = r0;
    *reinterpret_cast<float4*>(v_out + base + h1) = r1;

    if (tid < 128) {
        float4 w = *reinterpret_cast<const float4*>(whoT + (size_t)k * O_SZ + tid * 4);
        *reinterpret_cast<float4*>(out0 + (size_t)b * O_SZ + tid * 4) = w;
    }
}

// ---------------- bf16 split helpers ----------------

__device__ __forceinline__ unsigned short bf16_rn(float x) {
    unsigned u = __float_as_uint(x);
    unsigned r = (u + 0x7fffu + ((u >> 16) & 1u)) >> 16;
    return (unsigned short)r;
}

// precompute w_h2o bf16 hi/lo split once (removes 128x redundant per-tile split)
__global__ __launch_bounds__(256) void split_w_kernel(
    const float* __restrict__ W, unsigned short* __restrict__ Wh,
    unsigned short* __restrict__ Wl, int n) {
    int i = blockIdx.x * 256 + threadIdx.x;
    if (i * 4 >= n) return;
    float4 w4 = *reinterpret_cast<const float4*>(W + i * 4);
    float wv[4] = {w4.x, w4.y, w4.z, w4.w};
    unsigned short h4[4], l4[4];
#pragma unroll
    for (int e = 0; e < 4; ++e) {
        h4[e] = bf16_rn(wv[e]);
        float hf = __uint_as_float((unsigned)h4[e] << 16);
        l4[e] = bf16_rn(wv[e] - hf);
    }
    *reinterpret_cast<ushort4*>(Wh + i * 4) = make_ushort4(h4[0], h4[1], h4[2], h4[3]);
    *reinterpret_cast<ushort4*>(Wl + i * 4) = make_ushort4(l4[0], l4[1], l4[2], l4[3]);
}

// ---------------- output_potential GEMM: bf16x3 split MFMA, pre-split B (r22) ----------------

#define OBK 32

__global__ __launch_bounds__(256) void gemm_out1_bf16x3(
    const float* __restrict__ A,    // out_v [B,H]
    const unsigned short* __restrict__ Bh_g,   // pre-split w_h2o hi [O,H]
    const unsigned short* __restrict__ Bl_g,   // pre-split w_h2o lo [O,H]
    const float* __restrict__ bias0, float* __restrict__ C,
    const float* __restrict__ vminp, const float* __restrict__ vmaxp) {
    __shared__ unsigned short Ah[64][40], Al[64][40];
    __shared__ unsigned short Bh[64][40], Bl[64][40];
    const int tid = threadIdx.x;
    const int row0 = blockIdx.y * 64;   // batch rows
    const int col0 = blockIdx.x * 64;   // O cols
    const float vmin = *vminp, vmax = *vmaxp;
    const int wid = tid >> 6, lane = tid & 63;
    const int wrow = wid >> 1, wcol = wid & 1;
    const int lr = lane & 15;           // frag row/col
    const int lg = lane >> 4;           // k-group / D row group
    const int srow = tid >> 2;          // 0..63 staging row
    const int scol = (tid & 3) * 8;     // 0,8,16,24

    v4f acc[2][2];
#pragma unroll
    for (int i = 0; i < 2; ++i)
#pragma unroll
        for (int j = 0; j < 2; ++j) acc[i][j] = (v4f){0.f, 0.f, 0.f, 0.f};

    for (int k0 = 0; k0 < H_SZ; k0 += OBK) {
        // B staging: pure coalesced ushort copies (split precomputed)
        {
            ushort4 bh0 = *reinterpret_cast<const ushort4*>(
                Bh_g + (size_t)(col0 + srow) * H_SZ + k0 + scol);
            ushort4 bh1 = *reinterpret_cast<const ushort4*>(
                Bh_g + (size_t)(col0 + srow) * H_SZ + k0 + scol + 4);
            ushort4 bl0 = *reinterpret_cast<const ushort4*>(
                Bl_g + (size_t)(col0 + srow) * H_SZ + k0 + scol);
            ushort4 bl1 = *reinterpret_cast<const ushort4*>(
                Bl_g + (size_t)(col0 + srow) * H_SZ + k0 + scol + 4);
            *reinterpret_cast<ushort4*>(&Bh[srow][scol]) = bh0;
            *reinterpret_cast<ushort4*>(&Bh[srow][scol + 4]) = bh1;
            *reinterpret_cast<ushort4*>(&Bl[srow][scol]) = bl0;
            *reinterpret_cast<ushort4*>(&Bl[srow][scol + 4]) = bl1;
        }
        // A staging: load f32, clip, split (8x redundancy only)
#pragma unroll
        for (int p = 0; p < 2; ++p) {
            float4 a4 = *reinterpret_cast<const float4*>(
                A + (size_t)(row0 + srow) * H_SZ + k0 + scol + p * 4);
            float av[4] = {fminf(fmaxf(a4.x, vmin), vmax),
                           fminf(fmaxf(a4.y, vmin), vmax),
                           fminf(fmaxf(a4.z, vmin), vmax),
                           fminf(fmaxf(a4.w, vmin), vmax)};
#pragma unroll
            for (int e = 0; e < 4; ++e) {
                int cc = scol + p * 4 + e;
                unsigned short ha = bf16_rn(av[e]);
                float hfa = __uint_as_float((unsigned)ha << 16);
                Ah[srow][cc] = ha;
                Al[srow][cc] = bf16_rn(av[e] - hfa);
            }
        }
        __syncthreads();
        v8bf ah[2], al[2], bh[2], bl[2];
#pragma unroll
        for (int i = 0; i < 2; ++i) {
            ah[i] = *reinterpret_cast<const v8bf*>(&Ah[wrow * 32 + i * 16 + lr][lg * 8]);
            al[i] = *reinterpret_cast<const v8bf*>(&Al[wrow * 32 + i * 16 + lr][lg * 8]);
        }
#pragma unroll
        for (int j = 0; j < 2; ++j) {
            bh[j] = *reinterpret_cast<const v8bf*>(&Bh[wcol * 32 + j * 16 + lr][lg * 8]);
            bl[j] = *reinterpret_cast<const v8bf*>(&Bl[wcol * 32 + j * 16 + lr][lg * 8]);
        }
#pragma unroll
        for (int i = 0; i < 2; ++i)
#pragma unroll
            for (int j = 0; j < 2; ++j) {
                acc[i][j] = __builtin_amdgcn_mfma_f32_16x16x32_bf16(
                    ah[i], bh[j], acc[i][j], 0, 0, 0);
                acc[i][j] = __builtin_amdgcn_mfma_f32_16x16x32_bf16(
                    ah[i], bl[j], acc[i][j], 0, 0, 0);
                acc[i][j] = __builtin_amdgcn_mfma_f32_16x16x32_bf16(
                    al[i], bh[j], acc[i][j], 0, 0, 0);
            }
        __syncthreads();
    }
#pragma unroll
    for (int i = 0; i < 2; ++i)
#pragma unroll
        for (int j = 0; j < 2; ++j) {
            int gcol = col0 + wcol * 32 + j * 16 + lr;
            float bb = bias0[gcol];
#pragma unroll
            for (int q = 0; q < 4; ++q) {
                int grow = row0 + wrow * 32 + i * 16 + lg * 4 + q;  // blocked D
                C[(size_t)grow * O_SZ + gcol] = acc[i][j][q] + bb;
            }
        }
}

// ---------------- launch ----------------

extern "C" void kernel_launch(void* const* d_in, const int* in_sizes, int n_in,
                              void* d_out, int out_size, void* d_ws, size_t ws_size,
                              hipStream_t stream) {
    const float* in_spike = (const float*)d_in[0];
    const float* in_cur   = (const float*)d_in[1];
    const float* v_in     = (const float*)d_in[2];
    const float* t_in     = (const float*)d_in[3];
    const float* w_i2h    = (const float*)d_in[4];
    const float* b_i2h    = (const float*)d_in[5];
    const float* w_h2h    = (const float*)d_in[6];
    const float* b_h2h    = (const float*)d_in[7];
    const float* w_h2o    = (const float*)d_in[8];
    const float* b_h2o    = (const float*)d_in[9];
    const float* syn_p    = (const float*)d_in[10];
    const float* vmin_p   = (const float*)d_in[11];
    const float* vmax_p   = (const float*)d_in[12];

    float* out0    = (float*)d_out;                     // output_spike [B,O]
    float* out1    = out0 + (size_t)B_SZ * O_SZ;        // output_potential [B,O]
    float* out_v   = out1 + (size_t)B_SZ * O_SZ;        // v [B,H]
    float* out_t   = out_v + (size_t)B_SZ * H_SZ;       // t [B]
    float* out_mdt = out_t + B_SZ;                      // min_dt [B]
    float* out_kf  = out_mdt + B_SZ;                    // k (float) [B]

    // workspace: eta f32 [B,H] | kidx int [B] | whhT [H,H] | whoT [H,O]
    //            | Wh2o_hi ushort [O,H] | Wh2o_lo ushort [O,H]
    float* eta  = (float*)d_ws;
    int*   kidx = (int*)(eta + (size_t)B_SZ * H_SZ);
    float* whhT = (float*)(kidx + B_SZ);
    float* whoT = whhT + (size_t)H_SZ * H_SZ;
    unsigned short* Wh = (unsigned short*)(whoT + (size_t)H_SZ * O_SZ);
    unsigned short* Wl = Wh + (size_t)O_SZ * H_SZ;

    dim3 tb(32, 8);
    transpose_kernel<<<dim3(H_SZ / 32, H_SZ / 32), tb, 0, stream>>>(w_h2h, whhT,
                                                                    H_SZ, H_SZ);
    transpose_kernel<<<dim3(H_SZ / 32, O_SZ / 32), tb, 0, stream>>>(w_h2o, whoT,
                                                                    O_SZ, H_SZ);
    split_w_kernel<<<(O_SZ * H_SZ / 4 + 255) / 256, 256, 0, stream>>>(
        w_h2o, Wh, Wl, O_SZ * H_SZ);

    gemm_eta_mfma_f64<<<dim3(H_SZ / 128, B_SZ / 128), 512, 0, stream>>>(
        in_cur, w_i2h, b_i2h, b_h2h, eta);

    fused_row_kernel<<<B_SZ, 256, 0, stream>>>(
        v_in, in_spike, eta, t_in, syn_p, whhT, whoT,
        out_t, out_mdt, out_kf, kidx, out_v, out0);

    gemm_out1_bf16x3<<<dim3(O_SZ / 64, B_SZ / 64), 256, 0, stream>>>(
        out_v, Wh, Wl, b_h2o, out1, vmin_p, vmax_p);
}